// Round 8
// baseline (190.785 us; speedup 1.0000x reference)
//
#include <hip/hip_runtime.h>

typedef __attribute__((ext_vector_type(4)))  float f32x4;
typedef __attribute__((ext_vector_type(16))) float f32x16;
typedef __attribute__((ext_vector_type(8)))  short bf16x8;

__device__ __forceinline__ short f2bf(float f) {
    union { float f; unsigned u; } v; v.f = f;
    unsigned u = v.u + 0x7FFFu + ((v.u >> 16) & 1u);   // RNE
    return (short)(u >> 16);
}
__device__ __forceinline__ int pack_bf2(float a, float b) {
    union { float f; unsigned u; } ua, ub; ua.f = a; ub.f = b;
    unsigned x = ua.u + 0x8000u, y = ub.u + 0x8000u;   // round half-up
    return (int)__builtin_amdgcn_perm(y, x, 0x07060302u);
}

// ---------------------------------------------------------------------------
// Prep (16 blocks x 256): per component c
//   1. b = A m ; kscal = m^T A m
//   2. Bb32: bias GEMV A-operand frags (32x32x16), rows 0..15 = -2 b_c
//   3. in-LDS fp32 Cholesky A = L L^T (lower in place; upper keeps A)
//   4. LtF: Z-MFMA A-operand frags of L^T: frag f=(r*4+kc), lane L holds
//      Lt[m][k] = L[k][m], m=r*32+(L&31), k=kc*16+8*(L>>5)+j
// ---------------------------------------------------------------------------
__global__ void gmm_prep(const float* __restrict__ Ainv,
                         const float* __restrict__ means,
                         short* __restrict__ LtF,
                         short* __restrict__ Bb32,
                         float* __restrict__ kscal) {
    __shared__ float sA[64 * 68];
    __shared__ float sm[64];
    __shared__ float sb[64];
    const int c = blockIdx.x, t = threadIdx.x;
    const float* A = Ainv + c * 4096;
    #pragma unroll
    for (int i = 0; i < 4; ++i) {
        int flat = i * 1024 + t * 4;
        int r = flat >> 6, col = flat & 63;
        *(f32x4*)&sA[r * 68 + col] = *(const f32x4*)(A + flat);
    }
    if (t < 64) sm[t] = means[c * 64 + t];
    __syncthreads();
    {   // b[j] = A[j,:].m   (4 lanes per row)
        int j = t >> 2, seg = t & 3;
        float p = 0.f;
        #pragma unroll
        for (int k = 0; k < 16; ++k) p += sA[j * 68 + seg * 16 + k] * sm[seg * 16 + k];
        p += __shfl_xor(p, 1, 64); p += __shfl_xor(p, 2, 64);
        if ((t & 3) == 0) sb[j] = p;
    }
    __syncthreads();
    if (t < 64) {
        float km = sm[t] * sb[t];
        #pragma unroll
        for (int off = 32; off >= 1; off >>= 1) km += __shfl_xor(km, off, 64);
        if (t == 0) kscal[c] = km;
        // bias GEMV frags: row m = t&31 (comps 0..15 live, 16..31 zero)
        #pragma unroll
        for (int kc = 0; kc < 4; ++kc) {
            if ((t & 31) == c) {
                bf16x8 v;
                #pragma unroll
                for (int j = 0; j < 8; ++j)
                    v[j] = f2bf(-2.f * sb[kc * 16 + (t >> 5) * 8 + j]);
                *(bf16x8*)(Bb32 + kc * 512 + t * 8) = v;
            }
            if (c == 0 && (t & 31) >= 16) {
                bf16x8 z;
                #pragma unroll
                for (int j = 0; j < 8; ++j) z[j] = 0;
                *(bf16x8*)(Bb32 + kc * 512 + t * 8) = z;
            }
        }
    }
    // ---- Cholesky, right-looking, 4 threads per row (r=t>>2, seg s=t&3) ----
    const int r = t >> 2, s = t & 3;
    for (int k = 0; k < 64; ++k) {
        float dk = sA[k * 68 + k];
        float sq = sqrtf(dk), inv = 1.0f / sq;
        __syncthreads();
        if (s == 0 && r >= k)
            sA[r * 68 + k] = (r == k) ? sq : sA[r * 68 + k] * inv;
        __syncthreads();
        if (r > k) {
            float lrk = sA[r * 68 + k];
            int j0 = (k + 1 > s * 16) ? k + 1 : s * 16;
            int j1 = (r < s * 16 + 15) ? r : s * 16 + 15;
            for (int j = j0; j <= j1; ++j)
                sA[r * 68 + j] -= lrk * sA[j * 68 + k];
        }
        __syncthreads();
    }
    // ---- emit L^T fragments ----
    #pragma unroll
    for (int rep = 0; rep < 2; ++rep) {
        int idx = rep * 256 + t;            // 512 (frag,lane) slots
        int f = idx >> 6, L = idx & 63;
        int m = (f >> 2) * 32 + (L & 31);
        int kb = (f & 3) * 16 + (L >> 5) * 8;
        bf16x8 v;
        #pragma unroll
        for (int j = 0; j < 8; ++j) {
            int k = kb + j;
            v[j] = (m <= k) ? f2bf(sA[k * 68 + m]) : (short)0;
        }
        *(bf16x8*)(LtF + c * 4096 + f * 512 + L * 8) = v;
    }
}

union BFrag { bf16x8 v; int i[4]; };

// ---------------------------------------------------------------------------
// Main (1024 blocks x 256): wave w owns 64 samples = 2 tiles of 32 (32x32x16
// shape). x packed bf16 persistent in regs. L^T frags staged in LDS 4 comps
// at a time. d = sum_j (L^T x)_j^2 + lin, lin = -2b.x from a 4-MFMA GEMV
// parked in LDS; kscal/w via uniform LDS reads.
// ---------------------------------------------------------------------------
__global__ __launch_bounds__(256) void gmm_main(
    const float* __restrict__ X,
    const float* __restrict__ weights,
    const short* __restrict__ LtF,
    const short* __restrict__ Bb32,
    const float* __restrict__ kscal,
    float* __restrict__ out) {

    __shared__ short sAb[16384];          // 32 KB: 4 comps x 8 KB
    __shared__ float sLin[16 * 256];      // 16 KB: [comp][sample-in-block]
    __shared__ float sKW[32];             // [0..15]=kscal, [16..31]=w

    const int tid = threadIdx.x;
    const int lane = tid & 63, w = tid >> 6;
    const int h = lane >> 5, col = lane & 31;
    const int base = blockIdx.x * 256 + w * 64;
    const int boff = blockIdx.x & 3;

    // stage group boff (4 comps, 32 KB)
    {
        const int4* src = (const int4*)LtF + boff * 2048;
        #pragma unroll
        for (int i = 0; i < 8; ++i)
            ((int4*)sAb)[i * 256 + tid] = src[i * 256 + tid];
    }
    if (tid < 16) { sKW[tid] = kscal[tid]; sKW[16 + tid] = weights[tid]; }

    // x -> persistent packed bf16 B-frags (B[k][n]: n=lane&31, k=8h+j per chunk)
    BFrag xb[2][4];
    #pragma unroll
    for (int t = 0; t < 2; ++t) {
        const float* xr = X + (size_t)(base + t * 32 + col) * 64 + h * 8;
        #pragma unroll
        for (int kc = 0; kc < 4; ++kc) {
            f32x4 a = *(const f32x4*)(xr + kc * 16);
            f32x4 b = *(const f32x4*)(xr + kc * 16 + 4);
            xb[t][kc].i[0] = pack_bf2(a[0], a[1]);
            xb[t][kc].i[1] = pack_bf2(a[2], a[3]);
            xb[t][kc].i[2] = pack_bf2(b[0], b[1]);
            xb[t][kc].i[3] = pack_bf2(b[2], b[3]);
        }
    }

    // lin GEMV: lin[c][n] = -2 b_c . x_n  -> park in sLin
    {
        bf16x8 bb[4];
        #pragma unroll
        for (int kc = 0; kc < 4; ++kc)
            bb[kc] = *(const bf16x8*)(Bb32 + kc * 512 + lane * 8);
        #pragma unroll
        for (int t = 0; t < 2; ++t) {
            f32x16 acc;
            #pragma unroll
            for (int i = 0; i < 16; ++i) acc[i] = 0.f;
            #pragma unroll
            for (int kc = 0; kc < 4; ++kc)
                acc = __builtin_amdgcn_mfma_f32_32x32x16_bf16(
                    bb[kc], xb[t][kc].v, acc, 0, 0, 0);
            #pragma unroll
            for (int rg = 0; rg < 8; ++rg) {      // rows < 16 only
                int row = (rg & 3) + 8 * (rg >> 2) + 4 * h;
                sLin[row * 256 + w * 64 + t * 32 + col] = acc[rg];
            }
        }
    }
    __syncthreads();

    float slog[2] = {0.f, 0.f};

    #pragma unroll 1
    for (int gi = 0; gi < 4; ++gi) {
        const int g = (gi + boff) & 3;
        #pragma unroll 1
        for (int cl = 0; cl < 4; ++cl) {
            bf16x8 af[8];                 // frag f = r*4+kc
            #pragma unroll
            for (int f = 0; f < 8; ++f)
                af[f] = *(const bf16x8*)&sAb[cl * 4096 + f * 512 + lane * 8];
            const int c = g * 4 + cl;
            const float kc_ = sKW[c], wcc = sKW[16 + c];
            const float* lp = sLin + c * 256 + w * 64 + col;

            #pragma unroll
            for (int t = 0; t < 2; ++t) {
                f32x16 a0, a1;
                #pragma unroll
                for (int i = 0; i < 16; ++i) { a0[i] = 0.f; a1[i] = 0.f; }
                #pragma unroll
                for (int kc = 0; kc < 4; ++kc)
                    a0 = __builtin_amdgcn_mfma_f32_32x32x16_bf16(
                        af[kc], xb[t][kc].v, a0, 0, 0, 0);
                #pragma unroll
                for (int kc = 0; kc < 4; ++kc)
                    a1 = __builtin_amdgcn_mfma_f32_32x32x16_bf16(
                        af[4 + kc], xb[t][kc].v, a1, 0, 0, 0);
                float dp = 0.f;
                #pragma unroll
                for (int i = 0; i < 16; ++i)
                    dp += a0[i] * a0[i] + a1[i] * a1[i];
                dp += __shfl_xor(dp, 32, 64);     // other row-half
                float d = fmaxf(dp + lp[t * 32] + kc_, 1e-30f);
                slog[t] = fmaf(wcc, __builtin_amdgcn_logf(d), slog[t]);
            }
        }
        if (gi < 3) {                     // restage next group
            __syncthreads();
            const int4* src = (const int4*)LtF + (((gi + 1 + boff) & 3) * 2048);
            #pragma unroll
            for (int i = 0; i < 8; ++i)
                ((int4*)sAb)[i * 256 + tid] = src[i * 256 + tid];
            __syncthreads();
        }
    }

    if (lane < 32) {
        #pragma unroll
        for (int t = 0; t < 2; ++t)
            out[base + t * 32 + lane] = __builtin_amdgcn_exp2f(slog[t]);
    }
}

extern "C" void kernel_launch(void* const* d_in, const int* in_sizes, int n_in,
                              void* d_out, int out_size, void* d_ws, size_t ws_size,
                              hipStream_t stream) {
    const float* X       = (const float*)d_in[0];
    const float* Ainv    = (const float*)d_in[1];
    const float* means   = (const float*)d_in[2];
    const float* weights = (const float*)d_in[3];
    float* out = (float*)d_out;
    const int N = in_sizes[0] / 64;

    short* LtF   = (short*)d_ws;                       // 131072 B
    short* Bb32  = (short*)((char*)d_ws + 131072);     // 4096 B
    float* kscal = (float*)((char*)d_ws + 135168);     // 64 B

    gmm_prep<<<dim3(16), dim3(256), 0, stream>>>(Ainv, means, LtF, Bb32, kscal);
    gmm_main<<<dim3(N / 256), dim3(256), 0, stream>>>(X, weights, LtF, Bb32, kscal, out);
}